// Round 6
// baseline (957.295 us; speedup 1.0000x reference)
//
#include <hip/hip_runtime.h>
#include <hip/hip_bf16.h>
#include <math.h>

// ============================================================================
// Fractal-flame chaos game — bit-exact JAX RNG reproduction.
// R3: eliminate global atomics (measured hard wall ~19G atomics/s at the
// memory-side coherence point). Counting-sort splat records into 512 screen
// tiles (4 rows x 512 cols), accumulate per-tile in LDS (4-channel RGB+count,
// exploiting linearity of the colour transform), flush with plain stores,
// halo rows/cols via private scratch summed in compose. Zero memsets.
// ============================================================================

#define RNG_PARTITIONABLE 1
#define COLSUM_F32_ACCUM 1

typedef unsigned int u32;
typedef unsigned short u16;

static constexpr int FN = 8;
static constexpr int HH = 1024;
static constexpr int WW = 1024;
static constexpr int NP = 65536;
static constexpr int TI = 48;
static constexpr int WARM = 8;
static constexpr int HWPIX = HH * WW;
static constexpr int NSPLAT = TI - WARM;        // 40
static constexpr int NREC = NSPLAT * NP;        // 2,621,440
static constexpr int NBY = 256;                 // 4-row bands
static constexpr int NBX = 2;                   // 512-col chunks
static constexpr int NBKT = NBY * NBX;          // 512 buckets
static constexpr int NBLK = NP / 256;           // 256 chaos blocks
static constexpr int TROWS = 4, TCOLS = 512;
static constexpr int SCR_STRIDE = TCOLS + TROWS + 4;   // 520 float4 / bucket

static constexpr int META_CUMPT = 0;    // 64 f32
static constexpr int META_AFF   = 64;   // 48 f32
static constexpr int META_CT    = 112;  // 24 f32
static constexpr int META_BG    = 136;  // 3 f32
static constexpr int META_FLAG  = 139;  // 1 f32
static constexpr int META_KEYS  = 140;  // 96 u32
static constexpr int META_KX    = 236;  // 2 u32
static constexpr int META_K2S   = 238;  // 2 u32

struct U2 { u32 x, y; };

// ---------------------------------------------------------------- threefry2x32
__device__ __forceinline__ U2 tf2x32(u32 k0, u32 k1, u32 c0, u32 c1) {
  u32 ks2 = k0 ^ k1 ^ 0x1BD11BDAu;
  u32 x0 = c0 + k0, x1 = c1 + k1;
#define TF_R(r) { x0 += x1; x1 = (x1 << (r)) | (x1 >> (32 - (r))); x1 ^= x0; }
  TF_R(13) TF_R(15) TF_R(26) TF_R(6)
  x0 += k1; x1 += ks2 + 1u;
  TF_R(17) TF_R(29) TF_R(16) TF_R(24)
  x0 += ks2; x1 += k0 + 2u;
  TF_R(13) TF_R(15) TF_R(26) TF_R(6)
  x0 += k0; x1 += k1 + 3u;
  TF_R(17) TF_R(29) TF_R(16) TF_R(24)
  x0 += k1; x1 += ks2 + 4u;
  TF_R(13) TF_R(15) TF_R(26) TF_R(6)
  x0 += ks2; x1 += k0 + 5u;
#undef TF_R
  return {x0, x1};
}

__device__ __forceinline__ u32 rbits(U2 key, u32 i, u32 halfN) {
#if RNG_PARTITIONABLE
  (void)halfN;
  U2 r = tf2x32(key.x, key.y, 0u, i);
  return r.x ^ r.y;
#else
  if (i < halfN) { U2 r = tf2x32(key.x, key.y, i, i + halfN); return r.x; }
  else           { U2 r = tf2x32(key.x, key.y, i - halfN, i); return r.y; }
#endif
}

__device__ __forceinline__ float unitf(u32 b) {  // jax uniform [0,1)
  return __uint_as_float((b >> 9) | 0x3F800000u) - 1.0f;
}

// ---------------------------------------------------------------- bf16 helpers
__device__ __forceinline__ float bf2f(u16 h) { return __uint_as_float(((u32)h) << 16); }
__device__ __forceinline__ float rndbf(float x) {
  u32 u = __float_as_uint(x);
  u32 r = (u + 0x7FFFu + ((u >> 16) & 1u)) & 0xFFFF0000u;
  return __uint_as_float(r);
}
__device__ __forceinline__ float rnd_m(float x, bool bf) { return bf ? rndbf(x) : x; }
__device__ __forceinline__ float ldf(const void* p, int i, bool bf) {
  return bf ? bf2f(((const u16*)p)[i]) : ((const float*)p)[i];
}
__device__ __forceinline__ float exp_cr(float x) { return (float)exp((double)x); }
__device__ __forceinline__ float sigchain(float x, bool bf) {
  float e = rnd_m(exp_cr(-x), bf);
  float d = rnd_m(1.0f + e, bf);
  return rnd_m(1.0f / d, bf);
}

// ============================================================== setup kernel
__global__ __launch_bounds__(64) void setup_kernel(const void* pn, const void* affp,
                                                   const void* ctp, const void* bgp,
                                                   float* meta) {
  __shared__ int vote;
  __shared__ float sP[64];
  __shared__ u32 sroot[8];
  int tid = threadIdx.x;
  if (tid == 0) vote = 0;
  __syncthreads();
  {
    float v = fabsf(bf2f(((const u16*)pn)[tid]));
    if (v > 1e-4f && v < 16.0f) atomicAdd(&vote, 1);
  }
  __syncthreads();
  bool bf = (vote >= 50);

  if (tid == 0) {
    meta[META_FLAG] = bf ? 1.0f : 0.0f;
    u32* mu = (u32*)meta;
#if RNG_PARTITIONABLE
    U2 kx = tf2x32(0u, 42u, 0u, 0u);
    U2 ks = tf2x32(0u, 42u, 0u, 1u);
    U2 kl = tf2x32(0u, 42u, 0u, 2u);
    U2 k2 = tf2x32(ks.x, ks.y, 0u, 1u);
#else
    U2 t0 = tf2x32(0u, 42u, 0u, 3u), t1 = tf2x32(0u, 42u, 1u, 4u), t2 = tf2x32(0u, 42u, 2u, 5u);
    U2 kx{t0.x, t1.x}, ks{t2.x, t0.y}, kl{t1.y, t2.y};
    U2 r0 = tf2x32(ks.x, ks.y, 0u, 2u), r1 = tf2x32(ks.x, ks.y, 1u, 3u);
    U2 k2{r0.y, r1.y};
#endif
    sroot[0] = kx.x; sroot[1] = kx.y; sroot[2] = ks.x; sroot[3] = ks.y;
    sroot[4] = kl.x; sroot[5] = kl.y; sroot[6] = k2.x; sroot[7] = k2.y;
    mu[META_KX] = kx.x; mu[META_KX + 1] = kx.y;
    mu[META_K2S] = k2.x; mu[META_K2S + 1] = k2.y;
  }

  float c001 = bf ? 0.00099945068359375f : 0.001f;
  sP[tid] = rnd_m(sigchain(ldf(pn, tid, bf), bf) + c001, bf);
  if (tid < 48) meta[META_AFF + tid] = ldf(affp, tid, bf);
  if (tid < 24) meta[META_CT + tid] = sigchain(ldf(ctp, tid, bf), bf);
  if (tid < 3)  meta[META_BG + tid] = sigchain(ldf(bgp, tid, bf), bf);
  __syncthreads();

  if (tid < 48) {
    U2 kl{sroot[4], sroot[5]};
    u32* mu = (u32*)meta;
#if RNG_PARTITIONABLE
    U2 kt = tf2x32(kl.x, kl.y, 0u, (u32)tid);
#else
    u32 e0 = 2u * tid, e1 = 2u * tid + 1u;
    u32 w0 = (e0 < 48u) ? tf2x32(kl.x, kl.y, e0, e0 + 48u).x : tf2x32(kl.x, kl.y, e0 - 48u, e0).y;
    u32 w1 = (e1 < 48u) ? tf2x32(kl.x, kl.y, e1, e1 + 48u).x : tf2x32(kl.x, kl.y, e1 - 48u, e1).y;
    U2 kt{w0, w1};
#endif
    mu[META_KEYS + 2 * tid]     = kt.x;
    mu[META_KEYS + 2 * tid + 1] = kt.y;
  }

  if (tid < 8) {
    int c = tid;
    float a[8];
#if COLSUM_F32_ACCUM
    float cs = 0.0f;
    for (int r = 0; r < 8; ++r) cs += sP[r * 8 + c];
    cs = rnd_m(cs, bf);
#else
    float cs = 0.0f;
    for (int r = 0; r < 8; ++r) cs = rnd_m(cs + sP[r * 8 + c], bf);
#endif
    for (int r = 0; r < 8; ++r) a[r] = rnd_m(sP[r * 8 + c] / cs, bf);
    float b0 = rnd_m(a[0] + a[1], bf), b1 = rnd_m(a[2] + a[3], bf);
    float b2 = rnd_m(a[4] + a[5], bf), b3 = rnd_m(a[6] + a[7], bf);
    float c0 = rnd_m(b0 + b1, bf), c1v = rnd_m(b2 + b3, bf);
    float d0 = rnd_m(c0 + c1v, bf);
    float s5 = rnd_m(c0 + b2, bf);
    float cum[8] = { a[0], b0, rnd_m(b0 + a[2], bf), c0,
                     rnd_m(c0 + a[4], bf), s5, rnd_m(s5 + a[6], bf), d0 };
    for (int r = 0; r < 8; ++r) meta[META_CUMPT + c * 8 + r] = cum[r];
  }
}

// ====================================================== chaos + record kernel
__global__ __launch_bounds__(256) void chaos_record(const float* __restrict__ meta,
                                                    float4* __restrict__ recU,
                                                    u32* __restrict__ counts) {
  __shared__ float cumPT[64];
  __shared__ float aff8[64];
  __shared__ u32 keyw[96];
  __shared__ u32 rk[4];
  __shared__ u32 cnt[NBKT];
  int tid = threadIdx.x;
  if (tid < 64) cumPT[tid] = meta[META_CUMPT + tid];
  if (tid < 48) aff8[(tid / 6) * 8 + (tid % 6)] = meta[META_AFF + tid];
  const u32* mu = (const u32*)meta;
  if (tid < 96) keyw[tid] = mu[META_KEYS + tid];
  if (tid < 4)  rk[tid] = mu[META_KX + tid];
  for (int b = tid; b < NBKT; b += 256) cnt[b] = 0u;
  __syncthreads();

  u32 n = blockIdx.x * 256u + (u32)tid;
  U2 kx{rk[0], rk[1]}, k2{rk[2], rk[3]};
  float x = fmaxf(-1.0f, unitf(rbits(kx, 2u * n,      65536u)) * 2.0f - 1.0f);
  float y = fmaxf(-1.0f, unitf(rbits(kx, 2u * n + 1u, 65536u)) * 2.0f - 1.0f);
  int s = (int)(rbits(k2, n, 32768u) & 7u);

  float uv[8];
  // warmup batch (no records)
#pragma unroll
  for (int j = 0; j < 8; ++j) {
    U2 kt{keyw[2 * j], keyw[2 * j + 1]};
    uv[j] = unitf(rbits(kt, n, 32768u));
  }
#pragma unroll
  for (int j = 0; j < 8; ++j) {
    float u = uv[j];
    float4 c0 = *(const float4*)&cumPT[s * 8];
    float4 c1 = *(const float4*)&cumPT[s * 8 + 4];
    int cntc = (c0.x < u) + (c0.y < u) + (c0.z < u) + (c0.w < u)
             + (c1.x < u) + (c1.y < u) + (c1.z < u) + (c1.w < u);
    int nxt = cntc < 7 ? cntc : 7;
    float4 A0 = *(const float4*)&aff8[nxt * 8];
    float4 A1 = *(const float4*)&aff8[nxt * 8 + 4];
    float xn = A0.x * x + A0.y * y + A0.z;
    float yn = A0.w * x + A1.x * y + A1.y;
    x = xn; y = yn; s = nxt;
  }

  for (int b = 1; b < 6; ++b) {
#pragma unroll
    for (int j = 0; j < 8; ++j) {
      U2 kt{keyw[16 * b + 2 * j], keyw[16 * b + 2 * j + 1]};
      uv[j] = unitf(rbits(kt, n, 32768u));
    }
#pragma unroll
    for (int j = 0; j < 8; ++j) {
      float u = uv[j];
      float4 c0 = *(const float4*)&cumPT[s * 8];
      float4 c1 = *(const float4*)&cumPT[s * 8 + 4];
      int cntc = (c0.x < u) + (c0.y < u) + (c0.z < u) + (c0.w < u)
               + (c1.x < u) + (c1.y < u) + (c1.z < u) + (c1.w < u);
      int nxt = cntc < 7 ? cntc : 7;
      float4 A0 = *(const float4*)&aff8[nxt * 8];
      float4 A1 = *(const float4*)&aff8[nxt * 8 + 4];
      float xn = A0.x * x + A0.y * y + A0.z;
      float yn = A0.w * x + A1.x * y + A1.y;
      x = xn; y = yn; s = nxt;

      float gx = (x + 1.0f) * 0.5f * 1024.0f - 0.5f;
      float gy = (y + 1.0f) * 0.5f * 1024.0f - 0.5f;
      int xi = (int)floorf(gx), yi = (int)floorf(gy);
      u32 bkt = 0u, mval = 0xFFFFFFFFu;
      if (yi >= -1 && yi < 1024 && xi >= -1 && xi < 1024) {
        int yc = yi < 0 ? 0 : yi;
        int xc = xi < 0 ? 0 : xi;
        bkt = (u32)((yc >> 2) * NBX + (xc >> 9));
        mval = (u32)s;
        atomicAdd(&cnt[bkt], 1u);
      }
      recU[((b - 1) * 8 + j) * NP + n] =
          make_float4(gx, gy, __uint_as_float(mval), __uint_as_float(bkt));
    }
  }
  __syncthreads();
  for (int bb = tid; bb < NBKT; bb += 256) counts[bb * NBLK + blockIdx.x] = cnt[bb];
}

// ================================================== prefix kernels (counting sort)
__global__ __launch_bounds__(256) void pre_a(u32* __restrict__ counts,
                                             u32* __restrict__ totals) {
  int bkt = blockIdx.x, tid = threadIdx.x;
  __shared__ u32 sc[256];
  u32 v = counts[bkt * NBLK + tid];
  sc[tid] = v;
  __syncthreads();
  for (int off = 1; off < 256; off <<= 1) {
    u32 t = (tid >= off) ? sc[tid - off] : 0u;
    __syncthreads();
    sc[tid] += t;
    __syncthreads();
  }
  counts[bkt * NBLK + tid] = sc[tid] - v;     // exclusive within bucket
  if (tid == 255) totals[bkt] = sc[tid];
}

__global__ __launch_bounds__(512) void pre_b(const u32* __restrict__ totals,
                                             u32* __restrict__ starts) {
  int tid = threadIdx.x;
  __shared__ u32 sc[512];
  u32 v = totals[tid];
  sc[tid] = v;
  __syncthreads();
  for (int off = 1; off < 512; off <<= 1) {
    u32 t = (tid >= off) ? sc[tid - off] : 0u;
    __syncthreads();
    sc[tid] += t;
    __syncthreads();
  }
  starts[tid] = sc[tid] - v;
  if (tid == 511) starts[512] = sc[tid];
}

// ============================================================== scatter kernel
__global__ __launch_bounds__(256) void scatter_k(const float4* __restrict__ recU,
                                                 float4* __restrict__ recS,
                                                 const u32* __restrict__ counts,
                                                 const u32* __restrict__ starts) {
  __shared__ u32 cur[NBKT];
  int tid = threadIdx.x, blk = blockIdx.x;
  for (int b = tid; b < NBKT; b += 256) cur[b] = starts[b] + counts[b * NBLK + blk];
  __syncthreads();
  u32 n = (u32)blk * 256u + (u32)tid;
  for (int k = 0; k < NSPLAT; ++k) {
    float4 r = recU[k * NP + n];
    u32 m = __float_as_uint(r.z);
    if (m != 0xFFFFFFFFu) {
      u32 b = __float_as_uint(r.w);
      u32 pos = atomicAdd(&cur[b], 1u);
      recS[pos] = r;
    }
  }
}

// ================================================== per-bucket LDS accumulation
__global__ __launch_bounds__(256) void accum_k(const float4* __restrict__ recS,
                                               const u32* __restrict__ starts,
                                               const float* __restrict__ meta,
                                               float4* __restrict__ hist4,
                                               float4* __restrict__ scr) {
  __shared__ float tile[5 * 513 * 4];     // 41 KB: rows 0..3 own, 4 halo; col 512 halo
  __shared__ float4 ctv[8];
  int tid = threadIdx.x;
  int w = blockIdx.x;
  int by = w >> 1, jx = w & 1;
  for (int i = tid; i < 5 * 513 * 4; i += 256) tile[i] = 0.0f;
  if (tid < 8)
    ctv[tid] = make_float4(meta[META_CT + tid], meta[META_CT + 8 + tid],
                           meta[META_CT + 16 + tid], 1.0f);
  __syncthreads();

  u32 s0 = starts[w], e0 = starts[w + 1];
  for (u32 i = s0 + (u32)tid; i < e0; i += 256u) {
    float4 rec = recS[i];
    float gx = rec.x, gy = rec.y;
    u32 nxt = __float_as_uint(rec.z) & 7u;
    float fx0 = floorf(gx), fy0 = floorf(gy);
    float fx = gx - fx0, fy = gy - fy0;
    int xi = (int)fx0, yi = (int)fy0;
    float ofx = 1.0f - fx, ofy = 1.0f - fy;
    float wgt[4] = { ofx * ofy, fx * ofy, ofx * fy, fx * fy };
    float4 cv = ctv[nxt];
    int ry0 = yi - 4 * by, rx0 = xi - TCOLS * jx;
#pragma unroll
    for (int k = 0; k < 4; ++k) {
      int dy = k >> 1, dx = k & 1;
      if ((u32)(yi + dy) < 1024u && (u32)(xi + dx) < 1024u) {
        int idx = ((ry0 + dy) * 513 + (rx0 + dx)) * 4;
        float wv = wgt[k];
        atomicAdd(&tile[idx + 0], wv * cv.x);
        atomicAdd(&tile[idx + 1], wv * cv.y);
        atomicAdd(&tile[idx + 2], wv * cv.z);
        atomicAdd(&tile[idx + 3], wv);
      }
    }
  }
  __syncthreads();

  // flush own cells (plain stores; every pixel owned by exactly one bucket)
  for (int p = tid; p < TROWS * TCOLS; p += 256) {
    int ry = p >> 9, rx = p & 511;
    hist4[(by * 4 + ry) * 1024 + jx * TCOLS + rx] = *(const float4*)&tile[(ry * 513 + rx) * 4];
  }
  // halo: row 4 (512), col 512 (4 rows), corner (4,512)
  for (int p = tid; p < TCOLS; p += 256)
    scr[(size_t)w * SCR_STRIDE + p] = *(const float4*)&tile[(4 * 513 + p) * 4];
  if (tid < TROWS)
    scr[(size_t)w * SCR_STRIDE + TCOLS + tid] = *(const float4*)&tile[(tid * 513 + 512) * 4];
  if (tid == 0)
    scr[(size_t)w * SCR_STRIDE + TCOLS + TROWS] = *(const float4*)&tile[(4 * 513 + 512) * 4];
}

// ============================================================ compose kernel
__global__ __launch_bounds__(256) void compose_k(const float4* __restrict__ hist4,
                                                 const float4* __restrict__ scr,
                                                 const float* __restrict__ meta,
                                                 float* __restrict__ out) {
  int p = blockIdx.x * 256 + threadIdx.x;
  if (p >= HWPIX) return;
  int y = p >> 10, x = p & 1023;
  float4 v = hist4[p];
  if ((y & 3) == 0 && y > 0) {
    float4 a = scr[(size_t)(((y >> 2) - 1) * NBX + (x >> 9)) * SCR_STRIDE + (x & 511)];
    v.x += a.x; v.y += a.y; v.z += a.z; v.w += a.w;
  }
  if (x == 512) {
    float4 a = scr[(size_t)((y >> 2) * NBX) * SCR_STRIDE + TCOLS + (y & 3)];
    v.x += a.x; v.y += a.y; v.z += a.z; v.w += a.w;
    if ((y & 3) == 0 && y > 0) {
      float4 c2 = scr[(size_t)(((y >> 2) - 1) * NBX) * SCR_STRIDE + TCOLS + TROWS];
      v.x += c2.x; v.y += c2.y; v.z += c2.z; v.w += c2.w;
    }
  }
  bool bf = meta[META_FLAG] != 0.0f;
  float nexp = bf ? 0.10009765625f : 0.1f;
  float denom = v.w + 1e-5f;
  float alpha = fminf(fmaxf(log1pf(v.w * nexp), 0.0f), 1.0f);
  float oma = 1.0f - alpha;
  out[p]             = sqrtf(fmaxf((v.x / denom) * alpha, 1e-8f)) + meta[META_BG + 0] * oma;
  out[HWPIX + p]     = sqrtf(fmaxf((v.y / denom) * alpha, 1e-8f)) + meta[META_BG + 1] * oma;
  out[2 * HWPIX + p] = sqrtf(fmaxf((v.z / denom) * alpha, 1e-8f)) + meta[META_BG + 2] * oma;
}

// ================================================================= launcher
extern "C" void kernel_launch(void* const* d_in, const int* in_sizes, int n_in,
                              void* d_out, int out_size, void* d_ws, size_t ws_size,
                              hipStream_t stream) {
  (void)in_sizes; (void)n_in; (void)out_size; (void)ws_size;
  float4* recU = (float4*)d_ws;                       // 42 MB
  float4* recS = recU + NREC;                         // 42 MB
  float4* hist4 = recS + NREC;                        // 16 MB
  float4* scr = hist4 + HWPIX;                        // 4.3 MB
  u32* counts = (u32*)(scr + (size_t)NBKT * SCR_STRIDE);  // 512 KB
  u32* totals = counts + (size_t)NBKT * NBLK;         // 2 KB
  u32* starts = totals + NBKT;                        // 513 entries
  float* meta = (float*)(starts + 640);

  setup_kernel<<<1, 64, 0, stream>>>(d_in[0], d_in[1], d_in[2], d_in[3], meta);
  chaos_record<<<NBLK, 256, 0, stream>>>(meta, recU, counts);
  pre_a<<<NBKT, 256, 0, stream>>>(counts, totals);
  pre_b<<<1, 512, 0, stream>>>(totals, starts);
  scatter_k<<<NBLK, 256, 0, stream>>>(recU, recS, counts, starts);
  accum_k<<<NBKT, 256, 0, stream>>>(recS, starts, meta, hist4, scr);
  compose_k<<<(HWPIX + 255) / 256, 256, 0, stream>>>(hist4, scr, meta, (float*)d_out);
}

// Round 8
// 471.387 us; speedup vs baseline: 2.0308x; 2.0308x over previous
//
#include <hip/hip_runtime.h>
#include <hip/hip_bf16.h>
#include <math.h>

// ============================================================================
// Fractal-flame chaos game — bit-exact JAX RNG reproduction.
// R4 (resubmit after infra timeout): skew-proof accumulation. Counting-sort
// 8B splat records into 512 full-width 2-row bands; accumulation wgs each
// take a fixed 8192-record chunk of one band into a private LDS tile
// (4ch RGB+count), flush to private scratch with plain stores; compose sums
// the per-band partial tiles. No global atomics in the splat path; no memsets.
// ============================================================================

#define RNG_PARTITIONABLE 1
#define COLSUM_F32_ACCUM 1

typedef unsigned int u32;
typedef unsigned short u16;

static constexpr int FN = 8;
static constexpr int HH = 1024;
static constexpr int WW = 1024;
static constexpr int NP = 65536;
static constexpr int TI = 48;
static constexpr int WARM = 8;
static constexpr int HWPIX = HH * WW;
static constexpr int NSPLAT = TI - WARM;        // 40
static constexpr int NREC = NSPLAT * NP;        // 2,621,440
static constexpr int NBKT = 512;                // 2-row full-width bands
static constexpr int NBLK = NP / 256;           // 256 chaos blocks
static constexpr u32 CHUNK = 8192;              // records per accum wg
static constexpr int MAXWG = 2048;              // bound: 512 + 1280
static constexpr int TILE4 = 3 * 1024;          // float4 cells per partial tile

static constexpr int META_CUMPT = 0;    // 64 f32
static constexpr int META_AFF   = 64;   // 48 f32
static constexpr int META_CT    = 112;  // 24 f32
static constexpr int META_BG    = 136;  // 3 f32
static constexpr int META_FLAG  = 139;  // 1 f32
static constexpr int META_KEYS  = 140;  // 96 u32
static constexpr int META_KX    = 236;  // 2 u32
static constexpr int META_K2S   = 238;  // 2 u32

struct U2 { u32 x, y; };

// ---------------------------------------------------------------- threefry2x32
__device__ __forceinline__ U2 tf2x32(u32 k0, u32 k1, u32 c0, u32 c1) {
  u32 ks2 = k0 ^ k1 ^ 0x1BD11BDAu;
  u32 x0 = c0 + k0, x1 = c1 + k1;
#define TF_R(r) { x0 += x1; x1 = (x1 << (r)) | (x1 >> (32 - (r))); x1 ^= x0; }
  TF_R(13) TF_R(15) TF_R(26) TF_R(6)
  x0 += k1; x1 += ks2 + 1u;
  TF_R(17) TF_R(29) TF_R(16) TF_R(24)
  x0 += ks2; x1 += k0 + 2u;
  TF_R(13) TF_R(15) TF_R(26) TF_R(6)
  x0 += k0; x1 += k1 + 3u;
  TF_R(17) TF_R(29) TF_R(16) TF_R(24)
  x0 += k1; x1 += ks2 + 4u;
  TF_R(13) TF_R(15) TF_R(26) TF_R(6)
  x0 += ks2; x1 += k0 + 5u;
#undef TF_R
  return {x0, x1};
}

__device__ __forceinline__ u32 rbits(U2 key, u32 i, u32 halfN) {
#if RNG_PARTITIONABLE
  (void)halfN;
  U2 r = tf2x32(key.x, key.y, 0u, i);
  return r.x ^ r.y;
#else
  if (i < halfN) { U2 r = tf2x32(key.x, key.y, i, i + halfN); return r.x; }
  else           { U2 r = tf2x32(key.x, key.y, i - halfN, i); return r.y; }
#endif
}

__device__ __forceinline__ float unitf(u32 b) {  // jax uniform [0,1)
  return __uint_as_float((b >> 9) | 0x3F800000u) - 1.0f;
}

// ---------------------------------------------------------------- bf16 helpers
__device__ __forceinline__ float bf2f(u16 h) { return __uint_as_float(((u32)h) << 16); }
__device__ __forceinline__ float rndbf(float x) {
  u32 u = __float_as_uint(x);
  u32 r = (u + 0x7FFFu + ((u >> 16) & 1u)) & 0xFFFF0000u;
  return __uint_as_float(r);
}
__device__ __forceinline__ float rnd_m(float x, bool bf) { return bf ? rndbf(x) : x; }
__device__ __forceinline__ float ldf(const void* p, int i, bool bf) {
  return bf ? bf2f(((const u16*)p)[i]) : ((const float*)p)[i];
}
__device__ __forceinline__ float exp_cr(float x) { return (float)exp((double)x); }
__device__ __forceinline__ float sigchain(float x, bool bf) {
  float e = rnd_m(exp_cr(-x), bf);
  float d = rnd_m(1.0f + e, bf);
  return rnd_m(1.0f / d, bf);
}

// ============================================================== setup kernel
__global__ __launch_bounds__(64) void setup_kernel(const void* pn, const void* affp,
                                                   const void* ctp, const void* bgp,
                                                   float* meta) {
  __shared__ int vote;
  __shared__ float sP[64];
  __shared__ u32 sroot[8];
  int tid = threadIdx.x;
  if (tid == 0) vote = 0;
  __syncthreads();
  {
    float v = fabsf(bf2f(((const u16*)pn)[tid]));
    if (v > 1e-4f && v < 16.0f) atomicAdd(&vote, 1);
  }
  __syncthreads();
  bool bf = (vote >= 50);

  if (tid == 0) {
    meta[META_FLAG] = bf ? 1.0f : 0.0f;
    u32* mu = (u32*)meta;
#if RNG_PARTITIONABLE
    U2 kx = tf2x32(0u, 42u, 0u, 0u);
    U2 ks = tf2x32(0u, 42u, 0u, 1u);
    U2 kl = tf2x32(0u, 42u, 0u, 2u);
    U2 k2 = tf2x32(ks.x, ks.y, 0u, 1u);
#else
    U2 t0 = tf2x32(0u, 42u, 0u, 3u), t1 = tf2x32(0u, 42u, 1u, 4u), t2 = tf2x32(0u, 42u, 2u, 5u);
    U2 kx{t0.x, t1.x}, ks{t2.x, t0.y}, kl{t1.y, t2.y};
    U2 r0 = tf2x32(ks.x, ks.y, 0u, 2u), r1 = tf2x32(ks.x, ks.y, 1u, 3u);
    U2 k2{r0.y, r1.y};
#endif
    sroot[0] = kx.x; sroot[1] = kx.y; sroot[2] = ks.x; sroot[3] = ks.y;
    sroot[4] = kl.x; sroot[5] = kl.y; sroot[6] = k2.x; sroot[7] = k2.y;
    mu[META_KX] = kx.x; mu[META_KX + 1] = kx.y;
    mu[META_K2S] = k2.x; mu[META_K2S + 1] = k2.y;
  }

  float c001 = bf ? 0.00099945068359375f : 0.001f;
  sP[tid] = rnd_m(sigchain(ldf(pn, tid, bf), bf) + c001, bf);
  if (tid < 48) meta[META_AFF + tid] = ldf(affp, tid, bf);
  if (tid < 24) meta[META_CT + tid] = sigchain(ldf(ctp, tid, bf), bf);
  if (tid < 3)  meta[META_BG + tid] = sigchain(ldf(bgp, tid, bf), bf);
  __syncthreads();

  if (tid < 48) {
    U2 kl{sroot[4], sroot[5]};
    u32* mu = (u32*)meta;
#if RNG_PARTITIONABLE
    U2 kt = tf2x32(kl.x, kl.y, 0u, (u32)tid);
#else
    u32 e0 = 2u * tid, e1 = 2u * tid + 1u;
    u32 w0 = (e0 < 48u) ? tf2x32(kl.x, kl.y, e0, e0 + 48u).x : tf2x32(kl.x, kl.y, e0 - 48u, e0).y;
    u32 w1 = (e1 < 48u) ? tf2x32(kl.x, kl.y, e1, e1 + 48u).x : tf2x32(kl.x, kl.y, e1 - 48u, e1).y;
    U2 kt{w0, w1};
#endif
    mu[META_KEYS + 2 * tid]     = kt.x;
    mu[META_KEYS + 2 * tid + 1] = kt.y;
  }

  if (tid < 8) {
    int c = tid;
    float a[8];
#if COLSUM_F32_ACCUM
    float cs = 0.0f;
    for (int r = 0; r < 8; ++r) cs += sP[r * 8 + c];
    cs = rnd_m(cs, bf);
#else
    float cs = 0.0f;
    for (int r = 0; r < 8; ++r) cs = rnd_m(cs + sP[r * 8 + c], bf);
#endif
    for (int r = 0; r < 8; ++r) a[r] = rnd_m(sP[r * 8 + c] / cs, bf);
    float b0 = rnd_m(a[0] + a[1], bf), b1 = rnd_m(a[2] + a[3], bf);
    float b2 = rnd_m(a[4] + a[5], bf), b3 = rnd_m(a[6] + a[7], bf);
    float c0 = rnd_m(b0 + b1, bf), c1v = rnd_m(b2 + b3, bf);
    float d0 = rnd_m(c0 + c1v, bf);
    float s5 = rnd_m(c0 + b2, bf);
    float cum[8] = { a[0], b0, rnd_m(b0 + a[2], bf), c0,
                     rnd_m(c0 + a[4], bf), s5, rnd_m(s5 + a[6], bf), d0 };
    for (int r = 0; r < 8; ++r) meta[META_CUMPT + c * 8 + r] = cum[r];
  }
}

// ====================================================== chaos + record kernel
// 8B record: w0 = fxq<<16 | fyq (16-bit frac quantization);
//            w1 = s<<22 | (yi+1)<<11 | (xi+1);  w1==~0 => invalid (off-screen)
__global__ __launch_bounds__(256) void chaos_record(const float* __restrict__ meta,
                                                    uint2* __restrict__ recU,
                                                    u32* __restrict__ counts) {
  __shared__ float cumPT[64];
  __shared__ float aff8[64];
  __shared__ u32 keyw[96];
  __shared__ u32 rk[4];
  __shared__ u32 cnt[NBKT];
  int tid = threadIdx.x;
  if (tid < 64) cumPT[tid] = meta[META_CUMPT + tid];
  if (tid < 48) aff8[(tid / 6) * 8 + (tid % 6)] = meta[META_AFF + tid];
  const u32* mu = (const u32*)meta;
  if (tid < 96) keyw[tid] = mu[META_KEYS + tid];
  if (tid < 4)  rk[tid] = mu[META_KX + tid];
  for (int b = tid; b < NBKT; b += 256) cnt[b] = 0u;
  __syncthreads();

  u32 n = blockIdx.x * 256u + (u32)tid;
  U2 kx{rk[0], rk[1]}, k2{rk[2], rk[3]};
  float x = fmaxf(-1.0f, unitf(rbits(kx, 2u * n,      65536u)) * 2.0f - 1.0f);
  float y = fmaxf(-1.0f, unitf(rbits(kx, 2u * n + 1u, 65536u)) * 2.0f - 1.0f);
  int s = (int)(rbits(k2, n, 32768u) & 7u);

  float uv[8];
  // warmup batch (no records)
#pragma unroll
  for (int j = 0; j < 8; ++j) {
    U2 kt{keyw[2 * j], keyw[2 * j + 1]};
    uv[j] = unitf(rbits(kt, n, 32768u));
  }
#pragma unroll
  for (int j = 0; j < 8; ++j) {
    float u = uv[j];
    float4 c0 = *(const float4*)&cumPT[s * 8];
    float4 c1 = *(const float4*)&cumPT[s * 8 + 4];
    int cntc = (c0.x < u) + (c0.y < u) + (c0.z < u) + (c0.w < u)
             + (c1.x < u) + (c1.y < u) + (c1.z < u) + (c1.w < u);
    int nxt = cntc < 7 ? cntc : 7;
    float4 A0 = *(const float4*)&aff8[nxt * 8];
    float4 A1 = *(const float4*)&aff8[nxt * 8 + 4];
    float xn = A0.x * x + A0.y * y + A0.z;
    float yn = A0.w * x + A1.x * y + A1.y;
    x = xn; y = yn; s = nxt;
  }

  for (int b = 1; b < 6; ++b) {
#pragma unroll
    for (int j = 0; j < 8; ++j) {
      U2 kt{keyw[16 * b + 2 * j], keyw[16 * b + 2 * j + 1]};
      uv[j] = unitf(rbits(kt, n, 32768u));
    }
#pragma unroll
    for (int j = 0; j < 8; ++j) {
      float u = uv[j];
      float4 c0 = *(const float4*)&cumPT[s * 8];
      float4 c1 = *(const float4*)&cumPT[s * 8 + 4];
      int cntc = (c0.x < u) + (c0.y < u) + (c0.z < u) + (c0.w < u)
               + (c1.x < u) + (c1.y < u) + (c1.z < u) + (c1.w < u);
      int nxt = cntc < 7 ? cntc : 7;
      float4 A0 = *(const float4*)&aff8[nxt * 8];
      float4 A1 = *(const float4*)&aff8[nxt * 8 + 4];
      float xn = A0.x * x + A0.y * y + A0.z;
      float yn = A0.w * x + A1.x * y + A1.y;
      x = xn; y = yn; s = nxt;

      float gx = (x + 1.0f) * 0.5f * 1024.0f - 0.5f;
      float gy = (y + 1.0f) * 0.5f * 1024.0f - 0.5f;
      float fx0 = floorf(gx), fy0 = floorf(gy);
      float fx = gx - fx0, fy = gy - fy0;
      int xi = (int)fx0, yi = (int)fy0;
      u32 w0 = 0u, w1 = 0xFFFFFFFFu;
      if (yi >= -1 && yi < 1024 && xi >= -1 && xi < 1024) {
        int yc = yi < 0 ? 0 : yi;
        u32 fxq = (u32)(fx * 65536.0f); if (fxq > 65535u) fxq = 65535u;
        u32 fyq = (u32)(fy * 65536.0f); if (fyq > 65535u) fyq = 65535u;
        w0 = (fxq << 16) | fyq;
        w1 = ((u32)s << 22) | ((u32)(yi + 1) << 11) | (u32)(xi + 1);
        atomicAdd(&cnt[(u32)(yc >> 1)], 1u);
      }
      recU[((b - 1) * 8 + j) * NP + n] = make_uint2(w0, w1);
    }
  }
  __syncthreads();
  for (int bb = tid; bb < NBKT; bb += 256) counts[bb * NBLK + blockIdx.x] = cnt[bb];
}

// ================================================== prefix kernels (counting sort)
__global__ __launch_bounds__(256) void pre_a(u32* __restrict__ counts,
                                             u32* __restrict__ totals) {
  int bkt = blockIdx.x, tid = threadIdx.x;
  __shared__ u32 sc[256];
  u32 v = counts[bkt * NBLK + tid];
  sc[tid] = v;
  __syncthreads();
  for (int off = 1; off < 256; off <<= 1) {
    u32 t = (tid >= off) ? sc[tid - off] : 0u;
    __syncthreads();
    sc[tid] += t;
    __syncthreads();
  }
  counts[bkt * NBLK + tid] = sc[tid] - v;     // exclusive within bucket
  if (tid == 255) totals[bkt] = sc[tid];
}

__global__ __launch_bounds__(512) void pre_b(const u32* __restrict__ totals,
                                             u32* __restrict__ starts) {
  int tid = threadIdx.x;
  __shared__ u32 sc[512];
  u32 v = totals[tid];
  sc[tid] = v;
  __syncthreads();
  for (int off = 1; off < 512; off <<= 1) {
    u32 t = (tid >= off) ? sc[tid - off] : 0u;
    __syncthreads();
    sc[tid] += t;
    __syncthreads();
  }
  starts[tid] = sc[tid] - v;
  if (tid == 511) starts[512] = sc[tid];
}

// =============================================== chunk assignment (equal work)
__global__ __launch_bounds__(512) void assign_k(const u32* __restrict__ starts,
                                                u32* __restrict__ poff,
                                                u32* __restrict__ wgmap) {
  __shared__ u32 sc[512];
  int tid = threadIdx.x;
  u32 len = starts[tid + 1] - starts[tid];
  u32 np = (len + CHUNK - 1) / CHUNK;           // 0 if empty
  sc[tid] = np;
  __syncthreads();
  for (int off = 1; off < 512; off <<= 1) {
    u32 t = (tid >= off) ? sc[tid - off] : 0u;
    __syncthreads();
    sc[tid] += t;
    __syncthreads();
  }
  u32 excl = sc[tid] - np;
  poff[tid] = excl;
  if (tid == 511) poff[512] = sc[511];
  u32 total = sc[511];
  for (u32 j = 0; j < np; ++j) wgmap[excl + j] = ((u32)tid << 16) | j;
  for (u32 i = total + (u32)tid; i < (u32)MAXWG; i += 512u) wgmap[i] = 0xFFFFFFFFu;
}

// ================================= equal-work per-chunk LDS accumulation
__global__ __launch_bounds__(256) void accum_k(const uint2* __restrict__ recS,
                                               const u32* __restrict__ starts,
                                               const u32* __restrict__ wgmap,
                                               const float* __restrict__ meta,
                                               float4* __restrict__ scratch) {
  u32 a = wgmap[blockIdx.x];
  if (a == 0xFFFFFFFFu) return;
  __shared__ float4 tile4[TILE4];               // 3 rows x 1024 cols, rgbw — 48 KB
  __shared__ float4 ctv[8];
  int tid = threadIdx.x;
  int b = (int)(a >> 16);
  u32 j = a & 0xFFFFu;
  u32 rs = starts[b] + j * CHUNK;
  u32 re = starts[b + 1];
  u32 rlim = rs + CHUNK;
  if (rlim < re) re = rlim;

  for (int i = tid; i < TILE4; i += 256) tile4[i] = make_float4(0.f, 0.f, 0.f, 0.f);
  if (tid < 8)
    ctv[tid] = make_float4(meta[META_CT + tid], meta[META_CT + 8 + tid],
                           meta[META_CT + 16 + tid], 1.0f);
  __syncthreads();

  float* tile = (float*)tile4;
  for (u32 i = rs + (u32)tid; i < re; i += 256u) {
    uint2 r = recS[i];
    int xi = (int)(r.y & 0x7FFu) - 1;
    int yi = (int)((r.y >> 11) & 0x7FFu) - 1;
    u32 sfn = (r.y >> 22) & 7u;
    float fx = (float)(r.x >> 16) * (1.0f / 65536.0f);
    float fy = (float)(r.x & 0xFFFFu) * (1.0f / 65536.0f);
    float ofx = 1.0f - fx, ofy = 1.0f - fy;
    float wgt[4] = { ofx * ofy, fx * ofy, ofx * fy, fx * fy };
    float4 cv = ctv[sfn];
    int ry0 = yi - 2 * b;
#pragma unroll
    for (int k = 0; k < 4; ++k) {
      int dy = k >> 1, dx = k & 1;
      if ((u32)(yi + dy) < 1024u && (u32)(xi + dx) < 1024u) {
        int idx = ((ry0 + dy) * 1024 + (xi + dx)) * 4;
        float wv = wgt[k];
        atomicAdd(&tile[idx + 0], wv * cv.x);
        atomicAdd(&tile[idx + 1], wv * cv.y);
        atomicAdd(&tile[idx + 2], wv * cv.z);
        atomicAdd(&tile[idx + 3], wv);
      }
    }
  }
  __syncthreads();

  float4* dst = scratch + (size_t)blockIdx.x * TILE4;
  for (int i = tid; i < TILE4; i += 256) dst[i] = tile4[i];
}

// ============================================================ compose kernel
__global__ __launch_bounds__(256) void compose_k(const float4* __restrict__ scratch,
                                                 const u32* __restrict__ poff,
                                                 const float* __restrict__ meta,
                                                 float* __restrict__ out) {
  int p = blockIdx.x * 256 + threadIdx.x;
  if (p >= HWPIX) return;
  int y = p >> 10, x = p & 1023;
  int b = y >> 1, r = y & 1;
  float4 v = make_float4(0.f, 0.f, 0.f, 0.f);
  u32 k0 = poff[b], k1 = poff[b + 1];
  for (u32 k = k0; k < k1; ++k) {
    float4 a = scratch[(size_t)k * TILE4 + r * 1024 + x];
    v.x += a.x; v.y += a.y; v.z += a.z; v.w += a.w;
  }
  if (r == 0 && y > 0) {                  // halo row from band above
    u32 h0 = poff[b - 1], h1 = poff[b];
    for (u32 k = h0; k < h1; ++k) {
      float4 a = scratch[(size_t)k * TILE4 + 2 * 1024 + x];
      v.x += a.x; v.y += a.y; v.z += a.z; v.w += a.w;
    }
  }
  bool bf = meta[META_FLAG] != 0.0f;
  float nexp = bf ? 0.10009765625f : 0.1f;
  float denom = v.w + 1e-5f;
  float alpha = fminf(fmaxf(log1pf(v.w * nexp), 0.0f), 1.0f);
  float oma = 1.0f - alpha;
  out[p]             = sqrtf(fmaxf((v.x / denom) * alpha, 1e-8f)) + meta[META_BG + 0] * oma;
  out[HWPIX + p]     = sqrtf(fmaxf((v.y / denom) * alpha, 1e-8f)) + meta[META_BG + 1] * oma;
  out[2 * HWPIX + p] = sqrtf(fmaxf((v.z / denom) * alpha, 1e-8f)) + meta[META_BG + 2] * oma;
}

// ============================================================== scatter kernel
__global__ __launch_bounds__(256) void scatter_k(const uint2* __restrict__ recU,
                                                 uint2* __restrict__ recS,
                                                 const u32* __restrict__ counts,
                                                 const u32* __restrict__ starts) {
  __shared__ u32 cur[NBKT];
  int tid = threadIdx.x, blk = blockIdx.x;
  for (int b = tid; b < NBKT; b += 256) cur[b] = starts[b] + counts[b * NBLK + blk];
  __syncthreads();
  u32 n = (u32)blk * 256u + (u32)tid;
  for (int k = 0; k < NSPLAT; ++k) {
    uint2 r = recU[k * NP + n];
    if (r.y != 0xFFFFFFFFu) {
      int yi = (int)((r.y >> 11) & 0x7FFu) - 1;
      int yc = yi < 0 ? 0 : yi;
      u32 pos = atomicAdd(&cur[(u32)(yc >> 1)], 1u);
      recS[pos] = r;
    }
  }
}

// ================================================================= launcher
extern "C" void kernel_launch(void* const* d_in, const int* in_sizes, int n_in,
                              void* d_out, int out_size, void* d_ws, size_t ws_size,
                              hipStream_t stream) {
  (void)in_sizes; (void)n_in; (void)out_size; (void)ws_size;
  float4* scratch = (float4*)d_ws;                          // 2048*48KB = 96 MB (16B-aligned first)
  uint2* recU = (uint2*)(scratch + (size_t)MAXWG * TILE4);  // 21 MB
  uint2* recS = recU + NREC;                                // 21 MB
  u32* counts = (u32*)(recS + NREC);                        // 512*256*4 = 512 KB
  u32* totals = counts + (size_t)NBKT * NBLK;
  u32* starts = totals + NBKT;                              // 513
  u32* poff   = starts + 520;                               // 513
  u32* wgmap  = poff + 520;                                 // 2048
  float* meta = (float*)(wgmap + MAXWG);

  setup_kernel<<<1, 64, 0, stream>>>(d_in[0], d_in[1], d_in[2], d_in[3], meta);
  chaos_record<<<NBLK, 256, 0, stream>>>(meta, recU, counts);
  pre_a<<<NBKT, 256, 0, stream>>>(counts, totals);
  pre_b<<<1, 512, 0, stream>>>(totals, starts);
  assign_k<<<1, 512, 0, stream>>>(starts, poff, wgmap);
  scatter_k<<<NBLK, 256, 0, stream>>>(recU, recS, counts, starts);
  accum_k<<<MAXWG, 256, 0, stream>>>(recS, starts, wgmap, meta, scratch);
  compose_k<<<(HWPIX + 255) / 256, 256, 0, stream>>>(scratch, poff, meta, (float*)d_out);
}

// Round 9
// 467.641 us; speedup vs baseline: 2.0471x; 1.0080x over previous
//
#include <hip/hip_runtime.h>
#include <hip/hip_bf16.h>
#include <math.h>

// ============================================================================
// Fractal-flame chaos game — bit-exact JAX RNG reproduction.
// R5: R4 + per-thread register accumulator cache in accum_k. R4 evidence:
// accum_k 338us at VALUBusy 0.9% = same-address LDS-atomic serialization on
// hot attractor pixels. Cache (base-cell key -> 4x float4 corner sums) turns
// hot runs into register FMAs; flush only on pixel change. Uniform case pays
// ~20 VALU ops extra, nothing else. All other kernels identical to R4.
// ============================================================================

#define RNG_PARTITIONABLE 1
#define COLSUM_F32_ACCUM 1

typedef unsigned int u32;
typedef unsigned short u16;

static constexpr int FN = 8;
static constexpr int HH = 1024;
static constexpr int WW = 1024;
static constexpr int NP = 65536;
static constexpr int TI = 48;
static constexpr int WARM = 8;
static constexpr int HWPIX = HH * WW;
static constexpr int NSPLAT = TI - WARM;        // 40
static constexpr int NREC = NSPLAT * NP;        // 2,621,440
static constexpr int NBKT = 512;                // 2-row full-width bands
static constexpr int NBLK = NP / 256;           // 256 chaos blocks
static constexpr u32 CHUNK = 8192;              // records per accum wg
static constexpr int MAXWG = 2048;              // bound: 512 + 320
static constexpr int TILE4 = 3 * 1024;          // float4 cells per partial tile

static constexpr int META_CUMPT = 0;    // 64 f32
static constexpr int META_AFF   = 64;   // 48 f32
static constexpr int META_CT    = 112;  // 24 f32
static constexpr int META_BG    = 136;  // 3 f32
static constexpr int META_FLAG  = 139;  // 1 f32
static constexpr int META_KEYS  = 140;  // 96 u32
static constexpr int META_KX    = 236;  // 2 u32
static constexpr int META_K2S   = 238;  // 2 u32

struct U2 { u32 x, y; };

// ---------------------------------------------------------------- threefry2x32
__device__ __forceinline__ U2 tf2x32(u32 k0, u32 k1, u32 c0, u32 c1) {
  u32 ks2 = k0 ^ k1 ^ 0x1BD11BDAu;
  u32 x0 = c0 + k0, x1 = c1 + k1;
#define TF_R(r) { x0 += x1; x1 = (x1 << (r)) | (x1 >> (32 - (r))); x1 ^= x0; }
  TF_R(13) TF_R(15) TF_R(26) TF_R(6)
  x0 += k1; x1 += ks2 + 1u;
  TF_R(17) TF_R(29) TF_R(16) TF_R(24)
  x0 += ks2; x1 += k0 + 2u;
  TF_R(13) TF_R(15) TF_R(26) TF_R(6)
  x0 += k0; x1 += k1 + 3u;
  TF_R(17) TF_R(29) TF_R(16) TF_R(24)
  x0 += k1; x1 += ks2 + 4u;
  TF_R(13) TF_R(15) TF_R(26) TF_R(6)
  x0 += ks2; x1 += k0 + 5u;
#undef TF_R
  return {x0, x1};
}

__device__ __forceinline__ u32 rbits(U2 key, u32 i, u32 halfN) {
#if RNG_PARTITIONABLE
  (void)halfN;
  U2 r = tf2x32(key.x, key.y, 0u, i);
  return r.x ^ r.y;
#else
  if (i < halfN) { U2 r = tf2x32(key.x, key.y, i, i + halfN); return r.x; }
  else           { U2 r = tf2x32(key.x, key.y, i - halfN, i); return r.y; }
#endif
}

__device__ __forceinline__ float unitf(u32 b) {  // jax uniform [0,1)
  return __uint_as_float((b >> 9) | 0x3F800000u) - 1.0f;
}

// ---------------------------------------------------------------- bf16 helpers
__device__ __forceinline__ float bf2f(u16 h) { return __uint_as_float(((u32)h) << 16); }
__device__ __forceinline__ float rndbf(float x) {
  u32 u = __float_as_uint(x);
  u32 r = (u + 0x7FFFu + ((u >> 16) & 1u)) & 0xFFFF0000u;
  return __uint_as_float(r);
}
__device__ __forceinline__ float rnd_m(float x, bool bf) { return bf ? rndbf(x) : x; }
__device__ __forceinline__ float ldf(const void* p, int i, bool bf) {
  return bf ? bf2f(((const u16*)p)[i]) : ((const float*)p)[i];
}
__device__ __forceinline__ float exp_cr(float x) { return (float)exp((double)x); }
__device__ __forceinline__ float sigchain(float x, bool bf) {
  float e = rnd_m(exp_cr(-x), bf);
  float d = rnd_m(1.0f + e, bf);
  return rnd_m(1.0f / d, bf);
}

// ============================================================== setup kernel
__global__ __launch_bounds__(64) void setup_kernel(const void* pn, const void* affp,
                                                   const void* ctp, const void* bgp,
                                                   float* meta) {
  __shared__ int vote;
  __shared__ float sP[64];
  __shared__ u32 sroot[8];
  int tid = threadIdx.x;
  if (tid == 0) vote = 0;
  __syncthreads();
  {
    float v = fabsf(bf2f(((const u16*)pn)[tid]));
    if (v > 1e-4f && v < 16.0f) atomicAdd(&vote, 1);
  }
  __syncthreads();
  bool bf = (vote >= 50);

  if (tid == 0) {
    meta[META_FLAG] = bf ? 1.0f : 0.0f;
    u32* mu = (u32*)meta;
#if RNG_PARTITIONABLE
    U2 kx = tf2x32(0u, 42u, 0u, 0u);
    U2 ks = tf2x32(0u, 42u, 0u, 1u);
    U2 kl = tf2x32(0u, 42u, 0u, 2u);
    U2 k2 = tf2x32(ks.x, ks.y, 0u, 1u);
#else
    U2 t0 = tf2x32(0u, 42u, 0u, 3u), t1 = tf2x32(0u, 42u, 1u, 4u), t2 = tf2x32(0u, 42u, 2u, 5u);
    U2 kx{t0.x, t1.x}, ks{t2.x, t0.y}, kl{t1.y, t2.y};
    U2 r0 = tf2x32(ks.x, ks.y, 0u, 2u), r1 = tf2x32(ks.x, ks.y, 1u, 3u);
    U2 k2{r0.y, r1.y};
#endif
    sroot[0] = kx.x; sroot[1] = kx.y; sroot[2] = ks.x; sroot[3] = ks.y;
    sroot[4] = kl.x; sroot[5] = kl.y; sroot[6] = k2.x; sroot[7] = k2.y;
    mu[META_KX] = kx.x; mu[META_KX + 1] = kx.y;
    mu[META_K2S] = k2.x; mu[META_K2S + 1] = k2.y;
  }

  float c001 = bf ? 0.00099945068359375f : 0.001f;
  sP[tid] = rnd_m(sigchain(ldf(pn, tid, bf), bf) + c001, bf);
  if (tid < 48) meta[META_AFF + tid] = ldf(affp, tid, bf);
  if (tid < 24) meta[META_CT + tid] = sigchain(ldf(ctp, tid, bf), bf);
  if (tid < 3)  meta[META_BG + tid] = sigchain(ldf(bgp, tid, bf), bf);
  __syncthreads();

  if (tid < 48) {
    U2 kl{sroot[4], sroot[5]};
    u32* mu = (u32*)meta;
#if RNG_PARTITIONABLE
    U2 kt = tf2x32(kl.x, kl.y, 0u, (u32)tid);
#else
    u32 e0 = 2u * tid, e1 = 2u * tid + 1u;
    u32 w0 = (e0 < 48u) ? tf2x32(kl.x, kl.y, e0, e0 + 48u).x : tf2x32(kl.x, kl.y, e0 - 48u, e0).y;
    u32 w1 = (e1 < 48u) ? tf2x32(kl.x, kl.y, e1, e1 + 48u).x : tf2x32(kl.x, kl.y, e1 - 48u, e1).y;
    U2 kt{w0, w1};
#endif
    mu[META_KEYS + 2 * tid]     = kt.x;
    mu[META_KEYS + 2 * tid + 1] = kt.y;
  }

  if (tid < 8) {
    int c = tid;
    float a[8];
#if COLSUM_F32_ACCUM
    float cs = 0.0f;
    for (int r = 0; r < 8; ++r) cs += sP[r * 8 + c];
    cs = rnd_m(cs, bf);
#else
    float cs = 0.0f;
    for (int r = 0; r < 8; ++r) cs = rnd_m(cs + sP[r * 8 + c], bf);
#endif
    for (int r = 0; r < 8; ++r) a[r] = rnd_m(sP[r * 8 + c] / cs, bf);
    float b0 = rnd_m(a[0] + a[1], bf), b1 = rnd_m(a[2] + a[3], bf);
    float b2 = rnd_m(a[4] + a[5], bf), b3 = rnd_m(a[6] + a[7], bf);
    float c0 = rnd_m(b0 + b1, bf), c1v = rnd_m(b2 + b3, bf);
    float d0 = rnd_m(c0 + c1v, bf);
    float s5 = rnd_m(c0 + b2, bf);
    float cum[8] = { a[0], b0, rnd_m(b0 + a[2], bf), c0,
                     rnd_m(c0 + a[4], bf), s5, rnd_m(s5 + a[6], bf), d0 };
    for (int r = 0; r < 8; ++r) meta[META_CUMPT + c * 8 + r] = cum[r];
  }
}

// ====================================================== chaos + record kernel
// 8B record: w0 = fxq<<16 | fyq (16-bit frac quantization);
//            w1 = s<<22 | (yi+1)<<11 | (xi+1);  w1==~0 => invalid (off-screen)
__global__ __launch_bounds__(256) void chaos_record(const float* __restrict__ meta,
                                                    uint2* __restrict__ recU,
                                                    u32* __restrict__ counts) {
  __shared__ float cumPT[64];
  __shared__ float aff8[64];
  __shared__ u32 keyw[96];
  __shared__ u32 rk[4];
  __shared__ u32 cnt[NBKT];
  int tid = threadIdx.x;
  if (tid < 64) cumPT[tid] = meta[META_CUMPT + tid];
  if (tid < 48) aff8[(tid / 6) * 8 + (tid % 6)] = meta[META_AFF + tid];
  const u32* mu = (const u32*)meta;
  if (tid < 96) keyw[tid] = mu[META_KEYS + tid];
  if (tid < 4)  rk[tid] = mu[META_KX + tid];
  for (int b = tid; b < NBKT; b += 256) cnt[b] = 0u;
  __syncthreads();

  u32 n = blockIdx.x * 256u + (u32)tid;
  U2 kx{rk[0], rk[1]}, k2{rk[2], rk[3]};
  float x = fmaxf(-1.0f, unitf(rbits(kx, 2u * n,      65536u)) * 2.0f - 1.0f);
  float y = fmaxf(-1.0f, unitf(rbits(kx, 2u * n + 1u, 65536u)) * 2.0f - 1.0f);
  int s = (int)(rbits(k2, n, 32768u) & 7u);

  float uv[8];
  // warmup batch (no records)
#pragma unroll
  for (int j = 0; j < 8; ++j) {
    U2 kt{keyw[2 * j], keyw[2 * j + 1]};
    uv[j] = unitf(rbits(kt, n, 32768u));
  }
#pragma unroll
  for (int j = 0; j < 8; ++j) {
    float u = uv[j];
    float4 c0 = *(const float4*)&cumPT[s * 8];
    float4 c1 = *(const float4*)&cumPT[s * 8 + 4];
    int cntc = (c0.x < u) + (c0.y < u) + (c0.z < u) + (c0.w < u)
             + (c1.x < u) + (c1.y < u) + (c1.z < u) + (c1.w < u);
    int nxt = cntc < 7 ? cntc : 7;
    float4 A0 = *(const float4*)&aff8[nxt * 8];
    float4 A1 = *(const float4*)&aff8[nxt * 8 + 4];
    float xn = A0.x * x + A0.y * y + A0.z;
    float yn = A0.w * x + A1.x * y + A1.y;
    x = xn; y = yn; s = nxt;
  }

  for (int b = 1; b < 6; ++b) {
#pragma unroll
    for (int j = 0; j < 8; ++j) {
      U2 kt{keyw[16 * b + 2 * j], keyw[16 * b + 2 * j + 1]};
      uv[j] = unitf(rbits(kt, n, 32768u));
    }
#pragma unroll
    for (int j = 0; j < 8; ++j) {
      float u = uv[j];
      float4 c0 = *(const float4*)&cumPT[s * 8];
      float4 c1 = *(const float4*)&cumPT[s * 8 + 4];
      int cntc = (c0.x < u) + (c0.y < u) + (c0.z < u) + (c0.w < u)
               + (c1.x < u) + (c1.y < u) + (c1.z < u) + (c1.w < u);
      int nxt = cntc < 7 ? cntc : 7;
      float4 A0 = *(const float4*)&aff8[nxt * 8];
      float4 A1 = *(const float4*)&aff8[nxt * 8 + 4];
      float xn = A0.x * x + A0.y * y + A0.z;
      float yn = A0.w * x + A1.x * y + A1.y;
      x = xn; y = yn; s = nxt;

      float gx = (x + 1.0f) * 0.5f * 1024.0f - 0.5f;
      float gy = (y + 1.0f) * 0.5f * 1024.0f - 0.5f;
      float fx0 = floorf(gx), fy0 = floorf(gy);
      float fx = gx - fx0, fy = gy - fy0;
      int xi = (int)fx0, yi = (int)fy0;
      u32 w0 = 0u, w1 = 0xFFFFFFFFu;
      if (yi >= -1 && yi < 1024 && xi >= -1 && xi < 1024) {
        int yc = yi < 0 ? 0 : yi;
        u32 fxq = (u32)(fx * 65536.0f); if (fxq > 65535u) fxq = 65535u;
        u32 fyq = (u32)(fy * 65536.0f); if (fyq > 65535u) fyq = 65535u;
        w0 = (fxq << 16) | fyq;
        w1 = ((u32)s << 22) | ((u32)(yi + 1) << 11) | (u32)(xi + 1);
        atomicAdd(&cnt[(u32)(yc >> 1)], 1u);
      }
      recU[((b - 1) * 8 + j) * NP + n] = make_uint2(w0, w1);
    }
  }
  __syncthreads();
  for (int bb = tid; bb < NBKT; bb += 256) counts[bb * NBLK + blockIdx.x] = cnt[bb];
}

// ================================================== prefix kernels (counting sort)
__global__ __launch_bounds__(256) void pre_a(u32* __restrict__ counts,
                                             u32* __restrict__ totals) {
  int bkt = blockIdx.x, tid = threadIdx.x;
  __shared__ u32 sc[256];
  u32 v = counts[bkt * NBLK + tid];
  sc[tid] = v;
  __syncthreads();
  for (int off = 1; off < 256; off <<= 1) {
    u32 t = (tid >= off) ? sc[tid - off] : 0u;
    __syncthreads();
    sc[tid] += t;
    __syncthreads();
  }
  counts[bkt * NBLK + tid] = sc[tid] - v;     // exclusive within bucket
  if (tid == 255) totals[bkt] = sc[tid];
}

__global__ __launch_bounds__(512) void pre_b(const u32* __restrict__ totals,
                                             u32* __restrict__ starts) {
  int tid = threadIdx.x;
  __shared__ u32 sc[512];
  u32 v = totals[tid];
  sc[tid] = v;
  __syncthreads();
  for (int off = 1; off < 512; off <<= 1) {
    u32 t = (tid >= off) ? sc[tid - off] : 0u;
    __syncthreads();
    sc[tid] += t;
    __syncthreads();
  }
  starts[tid] = sc[tid] - v;
  if (tid == 511) starts[512] = sc[tid];
}

// =============================================== chunk assignment (equal work)
__global__ __launch_bounds__(512) void assign_k(const u32* __restrict__ starts,
                                                u32* __restrict__ poff,
                                                u32* __restrict__ wgmap) {
  __shared__ u32 sc[512];
  int tid = threadIdx.x;
  u32 len = starts[tid + 1] - starts[tid];
  u32 np = (len + CHUNK - 1) / CHUNK;           // 0 if empty
  sc[tid] = np;
  __syncthreads();
  for (int off = 1; off < 512; off <<= 1) {
    u32 t = (tid >= off) ? sc[tid - off] : 0u;
    __syncthreads();
    sc[tid] += t;
    __syncthreads();
  }
  u32 excl = sc[tid] - np;
  poff[tid] = excl;
  if (tid == 511) poff[512] = sc[511];
  u32 total = sc[511];
  for (u32 j = 0; j < np; ++j) wgmap[excl + j] = ((u32)tid << 16) | j;
  for (u32 i = total + (u32)tid; i < (u32)MAXWG; i += 512u) wgmap[i] = 0xFFFFFFFFu;
}

// ================================= equal-work per-chunk LDS accumulation
// Per-thread register cache: key = base cell index in tile (ry0*1024+xi),
// value = 4x float4 corner sums. Hot-pixel runs combine in registers; LDS
// ds_add only on key change. R4 evidence: same-address LDS atomic
// serialization was 338us; cache removes it on the hot path.
__global__ __launch_bounds__(256) void accum_k(const uint2* __restrict__ recS,
                                               const u32* __restrict__ starts,
                                               const u32* __restrict__ wgmap,
                                               const float* __restrict__ meta,
                                               float4* __restrict__ scratch) {
  u32 a = wgmap[blockIdx.x];
  if (a == 0xFFFFFFFFu) return;
  __shared__ float4 tile4[TILE4];               // 3 rows x 1024 cols, rgbw — 48 KB
  __shared__ float4 ctv[8];
  int tid = threadIdx.x;
  int b = (int)(a >> 16);
  u32 j = a & 0xFFFFu;
  u32 rs = starts[b] + j * CHUNK;
  u32 re = starts[b + 1];
  u32 rlim = rs + CHUNK;
  if (rlim < re) re = rlim;

  for (int i = tid; i < TILE4; i += 256) tile4[i] = make_float4(0.f, 0.f, 0.f, 0.f);
  if (tid < 8)
    ctv[tid] = make_float4(meta[META_CT + tid], meta[META_CT + 8 + tid],
                           meta[META_CT + 16 + tid], 1.0f);
  __syncthreads();

  float* tile = (float*)tile4;
  const int IKEY_INVALID = 0x7FFFFFFF;
  int ikey_c = IKEY_INVALID;
  u32 mask_c = 0u;
  float4 s00 = make_float4(0.f, 0.f, 0.f, 0.f);
  float4 s10 = s00, s01 = s00, s11 = s00;

#define FLUSH_CACHE() do { \
    if (ikey_c != IKEY_INVALID) { \
      if (mask_c & 1u) { int q = ikey_c * 4; \
        atomicAdd(&tile[q], s00.x); atomicAdd(&tile[q + 1], s00.y); \
        atomicAdd(&tile[q + 2], s00.z); atomicAdd(&tile[q + 3], s00.w); } \
      if (mask_c & 2u) { int q = (ikey_c + 1) * 4; \
        atomicAdd(&tile[q], s10.x); atomicAdd(&tile[q + 1], s10.y); \
        atomicAdd(&tile[q + 2], s10.z); atomicAdd(&tile[q + 3], s10.w); } \
      if (mask_c & 4u) { int q = (ikey_c + 1024) * 4; \
        atomicAdd(&tile[q], s01.x); atomicAdd(&tile[q + 1], s01.y); \
        atomicAdd(&tile[q + 2], s01.z); atomicAdd(&tile[q + 3], s01.w); } \
      if (mask_c & 8u) { int q = (ikey_c + 1025) * 4; \
        atomicAdd(&tile[q], s11.x); atomicAdd(&tile[q + 1], s11.y); \
        atomicAdd(&tile[q + 2], s11.z); atomicAdd(&tile[q + 3], s11.w); } \
    } } while (0)

  for (u32 i = rs + (u32)tid; i < re; i += 256u) {
    uint2 r = recS[i];
    int xi = (int)(r.y & 0x7FFu) - 1;
    int yi = (int)((r.y >> 11) & 0x7FFu) - 1;
    u32 sfn = (r.y >> 22) & 7u;
    float fx = (float)(r.x >> 16) * (1.0f / 65536.0f);
    float fy = (float)(r.x & 0xFFFFu) * (1.0f / 65536.0f);
    float ofx = 1.0f - fx, ofy = 1.0f - fy;
    float w00 = ofx * ofy, w10 = fx * ofy, w01 = ofx * fy, w11 = fx * fy;
    float4 cv = ctv[sfn];
    int ikey = (yi - 2 * b) * 1024 + xi;
    if (ikey != ikey_c) {
      FLUSH_CACHE();
      ikey_c = ikey;
      u32 m = 0u;
      if ((u32)yi < 1024u) {
        if ((u32)xi < 1024u)       m |= 1u;
        if ((u32)(xi + 1) < 1024u) m |= 2u;
      }
      if ((u32)(yi + 1) < 1024u) {
        if ((u32)xi < 1024u)       m |= 4u;
        if ((u32)(xi + 1) < 1024u) m |= 8u;
      }
      mask_c = m;
      s00 = make_float4(0.f, 0.f, 0.f, 0.f);
      s10 = s00; s01 = s00; s11 = s00;
    }
    s00.x += w00 * cv.x; s00.y += w00 * cv.y; s00.z += w00 * cv.z; s00.w += w00;
    s10.x += w10 * cv.x; s10.y += w10 * cv.y; s10.z += w10 * cv.z; s10.w += w10;
    s01.x += w01 * cv.x; s01.y += w01 * cv.y; s01.z += w01 * cv.z; s01.w += w01;
    s11.x += w11 * cv.x; s11.y += w11 * cv.y; s11.z += w11 * cv.z; s11.w += w11;
  }
  FLUSH_CACHE();
#undef FLUSH_CACHE
  __syncthreads();

  float4* dst = scratch + (size_t)blockIdx.x * TILE4;
  for (int i = tid; i < TILE4; i += 256) dst[i] = tile4[i];
}

// ============================================================ compose kernel
__global__ __launch_bounds__(256) void compose_k(const float4* __restrict__ scratch,
                                                 const u32* __restrict__ poff,
                                                 const float* __restrict__ meta,
                                                 float* __restrict__ out) {
  int p = blockIdx.x * 256 + threadIdx.x;
  if (p >= HWPIX) return;
  int y = p >> 10, x = p & 1023;
  int b = y >> 1, r = y & 1;
  float4 v = make_float4(0.f, 0.f, 0.f, 0.f);
  u32 k0 = poff[b], k1 = poff[b + 1];
  for (u32 k = k0; k < k1; ++k) {
    float4 a = scratch[(size_t)k * TILE4 + r * 1024 + x];
    v.x += a.x; v.y += a.y; v.z += a.z; v.w += a.w;
  }
  if (r == 0 && y > 0) {                  // halo row from band above
    u32 h0 = poff[b - 1], h1 = poff[b];
    for (u32 k = h0; k < h1; ++k) {
      float4 a = scratch[(size_t)k * TILE4 + 2 * 1024 + x];
      v.x += a.x; v.y += a.y; v.z += a.z; v.w += a.w;
    }
  }
  bool bf = meta[META_FLAG] != 0.0f;
  float nexp = bf ? 0.10009765625f : 0.1f;
  float denom = v.w + 1e-5f;
  float alpha = fminf(fmaxf(log1pf(v.w * nexp), 0.0f), 1.0f);
  float oma = 1.0f - alpha;
  out[p]             = sqrtf(fmaxf((v.x / denom) * alpha, 1e-8f)) + meta[META_BG + 0] * oma;
  out[HWPIX + p]     = sqrtf(fmaxf((v.y / denom) * alpha, 1e-8f)) + meta[META_BG + 1] * oma;
  out[2 * HWPIX + p] = sqrtf(fmaxf((v.z / denom) * alpha, 1e-8f)) + meta[META_BG + 2] * oma;
}

// ============================================================== scatter kernel
__global__ __launch_bounds__(256) void scatter_k(const uint2* __restrict__ recU,
                                                 uint2* __restrict__ recS,
                                                 const u32* __restrict__ counts,
                                                 const u32* __restrict__ starts) {
  __shared__ u32 cur[NBKT];
  int tid = threadIdx.x, blk = blockIdx.x;
  for (int b = tid; b < NBKT; b += 256) cur[b] = starts[b] + counts[b * NBLK + blk];
  __syncthreads();
  u32 n = (u32)blk * 256u + (u32)tid;
  for (int k = 0; k < NSPLAT; ++k) {
    uint2 r = recU[k * NP + n];
    if (r.y != 0xFFFFFFFFu) {
      int yi = (int)((r.y >> 11) & 0x7FFu) - 1;
      int yc = yi < 0 ? 0 : yi;
      u32 pos = atomicAdd(&cur[(u32)(yc >> 1)], 1u);
      recS[pos] = r;
    }
  }
}

// ================================================================= launcher
extern "C" void kernel_launch(void* const* d_in, const int* in_sizes, int n_in,
                              void* d_out, int out_size, void* d_ws, size_t ws_size,
                              hipStream_t stream) {
  (void)in_sizes; (void)n_in; (void)out_size; (void)ws_size;
  float4* scratch = (float4*)d_ws;                          // 2048*48KB = 96 MB
  uint2* recU = (uint2*)(scratch + (size_t)MAXWG * TILE4);  // 21 MB
  uint2* recS = recU + NREC;                                // 21 MB
  u32* counts = (u32*)(recS + NREC);                        // 512 KB
  u32* totals = counts + (size_t)NBKT * NBLK;
  u32* starts = totals + NBKT;                              // 513
  u32* poff   = starts + 520;                               // 513
  u32* wgmap  = poff + 520;                                 // 2048
  float* meta = (float*)(wgmap + MAXWG);

  setup_kernel<<<1, 64, 0, stream>>>(d_in[0], d_in[1], d_in[2], d_in[3], meta);
  chaos_record<<<NBLK, 256, 0, stream>>>(meta, recU, counts);
  pre_a<<<NBKT, 256, 0, stream>>>(counts, totals);
  pre_b<<<1, 512, 0, stream>>>(totals, starts);
  assign_k<<<1, 512, 0, stream>>>(starts, poff, wgmap);
  scatter_k<<<NBLK, 256, 0, stream>>>(recU, recS, counts, starts);
  accum_k<<<MAXWG, 256, 0, stream>>>(recS, starts, wgmap, meta, scratch);
  compose_k<<<(HWPIX + 255) / 256, 256, 0, stream>>>(scratch, poff, meta, (float*)d_out);
}